// Round 5
// baseline (155.089 us; speedup 1.0000x reference)
//
#include <hip/hip_runtime.h>

// FullScan via bf16 MFMA 32x32x16, full-M packing.
// out[k,t] = sum_{d<16,w<64} x[d,t+w]*P[k,d,w], K=8, L=1e6.
// M=32 rows = (k, tap-group g): row m = k + 8g (g covers taps [16g,16g+16)).
//   D_g[k](s) = sum_{c<16,d} P[k,d,16g+c] x[d,s+c]
//   out[k,t]  = sum_g D_g[k](t + 16g)
// Chunk c: reduction r = d. Lane l: n=l&31, h=l>>5; B frag elem j: r=8h+j ->
// 8 contiguous d -> aligned ds_read_b128 from d-major xs[pos][16] (swizzled).
// C/D: col=lane&31, row=(reg&3)+8*(reg>>2)+4h => reg kk+4g = D_g[kk+4h](n).
// R5: staging restructured for MLP depth 16 (5 outer iters x 16 independent
//     scalar loads, one drain each) -- R4's per-iter vmcnt(0) serialization
//     (18 x ~900cyc) was the dominant stall. Edge work moved to prep kernel.

constexpr int D    = 16;
constexpr int L    = 1000000;
constexpr int W    = 64;
constexpr int K    = 8;
constexpr int PADL = 31;
constexpr int NMID = L - W + 1;          // 999937
constexpr int TPB  = 256;                // 4 waves
constexpr int OTW  = 8;                  // out 32-pos tiles per wave
constexpr int CTW  = OTW + 2;            // computed tiles per wave
constexpr int BLK_OUT = 4 * OTW * 32;    // 1024 positions per block
constexpr int XS   = 1104;               // staged positions (need 1103)
constexpr int NBLK = (NMID + BLK_OUT - 1) / BLK_OUT;   // 977

typedef __attribute__((ext_vector_type(8)))  short short8;
typedef __attribute__((ext_vector_type(16))) float floatx16;

__device__ __forceinline__ unsigned short f2bf(float f) {
    union { float f; unsigned u; } v; v.f = f;
    unsigned u = v.u + 0x7fff + ((v.u >> 16) & 1);   // RNE
    return (unsigned short)(u >> 16);
}

__global__ __launch_bounds__(TPB, 3) void fullscan_mid(
    const float* __restrict__ x,
    const unsigned short* __restrict__ afr, float* __restrict__ out)
{
    __shared__ __align__(16) unsigned short xs[XS * 16];   // 35328 B
    const int tid = threadIdx.x;
    const int s0  = blockIdx.x * BLK_OUT;
    const int lane = tid & 63;
    const int wv   = tid >> 6;

    // ---- Stage x -> LDS (bf16, d-major, swizzled), MLP depth 16 ----
    // Thread (pl, dq): 4 d-rows at position strips pl, pl+64, pl+128, pl+192.
    {
        const int pl = tid & 63;
        const int dq = tid >> 6;            // d-quad 0..3
        const float* xr0 = x + (4 * dq + 0) * L + s0;
        const float* xr1 = x + (4 * dq + 1) * L + s0;
        const float* xr2 = x + (4 * dq + 2) * L + s0;
        const float* xr3 = x + (4 * dq + 3) * L + s0;
#pragma unroll 1
        for (int b0 = 0; b0 < XS; b0 += 256) {
            float v[4][4];
            // 16 independent loads in flight before any consumption.
#pragma unroll
            for (int s = 0; s < 4; ++s) {
                const int pos = b0 + 64 * s + pl;
                const bool ok = (pos < XS) && (s0 + pos < L);
                v[s][0] = ok ? xr0[pos] : 0.0f;
                v[s][1] = ok ? xr1[pos] : 0.0f;
                v[s][2] = ok ? xr2[pos] : 0.0f;
                v[s][3] = ok ? xr3[pos] : 0.0f;
            }
#pragma unroll
            for (int s = 0; s < 4; ++s) {
                const int pos = b0 + 64 * s + pl;
                if (pos < XS) {
                    unsigned long long w =
                        (unsigned long long)f2bf(v[s][0])
                      | ((unsigned long long)f2bf(v[s][1]) << 16)
                      | ((unsigned long long)f2bf(v[s][2]) << 32)
                      | ((unsigned long long)f2bf(v[s][3]) << 48);
                    const int swz = (pos >> 2) & 1;
                    *(unsigned long long*)&xs[pos * 16 + ((dq * 4) ^ (swz * 8))] = w;
                }
            }
        }
    }

    // Resident A fragments (issued after staging loads; latency hides under
    // the barrier wait).
    short8 A[16];
#pragma unroll
    for (int c = 0; c < 16; ++c)
        A[c] = *(const short8*)(afr + (c * 64 + lane) * 8);

    __syncthreads();

    const int n  = lane & 31;
    const int h  = lane >> 5;
    const int hb = h * 8;
    const int wbase = wv * OTW;             // first local out-tile of this wave

    floatx16 accW[3];

#pragma unroll
    for (int jj = 0; jj < CTW; ++jj) {
        floatx16 acc;
#pragma unroll
        for (int r = 0; r < 16; ++r) acc[r] = 0.0f;
        const int p0 = (wbase + jj) * 32 + n;

        // Software-pipelined chunk loop: prefetch B for c+1 before MFMA c.
        short8 Bc = *(const short8*)
            &xs[p0 * 16 + (hb ^ (((p0 >> 2) & 1) * 8))];
#pragma unroll
        for (int c = 0; c < 16; ++c) {
            short8 Bn = Bc;
            if (c < 15) {
                const int pos = p0 + c + 1;
                Bn = *(const short8*)
                    &xs[pos * 16 + (hb ^ (((pos >> 2) & 1) * 8))];
            }
            acc = __builtin_amdgcn_mfma_f32_32x32x16_bf16(A[c], Bc, acc, 0, 0, 0);
            Bc = Bn;
        }
        accW[jj % 3] = acc;

        if (jj >= 2) {
            const int ot = jj - 2;
            const floatx16 a0 = accW[(jj - 2) % 3];   // tile ot
            const floatx16 a1 = accW[(jj - 1) % 3];   // tile ot+1
            const floatx16 a2 = accW[jj % 3];         // tile ot+2
            const int t = s0 + (wbase + ot) * 32 + n;
#pragma unroll
            for (int kk = 0; kk < 4; ++kk) {
                const float g1t = (n >= 16) ? a0[kk + 4]  : a1[kk + 4];
                const float g3t = (n >= 16) ? a1[kk + 12] : a2[kk + 12];
                const float v = a0[kk] + a1[kk + 8]
                              + __shfl_xor(g1t, 16, 64)
                              + __shfl_xor(g3t, 16, 64);
                if (t < NMID)
                    out[(kk + 4 * h) * L + PADL + t] = v;
            }
        }
    }
}

// Prep: blocks 0..31 build the A-fragment table; blocks 32..39 compute the
// 63 edge outputs for k = bid-32 (fp32 exact).
// afr[c][lane][j] = bf16(P[k,d,w]), m=lane&31, h=lane>>5, k=m&7, g=m>>3,
// d=8h+j, w=16g+c.
__global__ void fullscan_prep(
    const float* __restrict__ x, const float* __restrict__ P,
    unsigned short* __restrict__ afr, float* __restrict__ out)
{
    const int bid = blockIdx.x;
    if (bid < 32) {
        const int u = bid * 256 + threadIdx.x;   // 32 blocks x 256 = 8192
        const int c = u >> 9, lane = (u >> 3) & 63, j = u & 7;
        const int m = lane & 31, h = lane >> 5;
        const int k = m & 7, g = m >> 3;
        const int d = 8 * h + j;
        const int w = 16 * g + c;
        afr[u] = f2bf(P[(k * D + d) * W + w]);
        return;
    }
    const int k = bid - 32;
    const int j = threadIdx.x;
    if (j < PADL) {
        float acc = 0.0f;
        for (int m = 0; m <= 32 + j; ++m)
#pragma unroll
            for (int d = 0; d < D; ++d)
                acc = fmaf(x[d * L + m], P[(k * D + d) * W + m], acc);
        out[k * L + j] = acc;
    } else if (j < 2 * PADL + 1) {
        const int jj = j - PADL;                  // 0..31
        float acc = 0.0f;
        for (int m = jj + 1; m < W; ++m)
#pragma unroll
            for (int d = 0; d < D; ++d)
                acc = fmaf(x[d * L + (L - W) + m], P[(k * D + d) * W + m], acc);
        out[k * L + PADL + NMID + jj] = acc;
    }
}

extern "C" void kernel_launch(void* const* d_in, const int* in_sizes, int n_in,
                              void* d_out, int out_size, void* d_ws, size_t ws_size,
                              hipStream_t stream)
{
    const float* x = (const float*)d_in[0];   // (D, L)
    const float* P = (const float*)d_in[1];   // (K, D, W)
    float* out = (float*)d_out;
    unsigned short* afr = (unsigned short*)d_ws;   // 16 KB

    hipLaunchKernelGGL(fullscan_prep, dim3(40), dim3(256), 0, stream,
                       x, P, afr, out);
    hipLaunchKernelGGL(fullscan_mid, dim3(NBLK), dim3(TPB), 0, stream,
                       x, afr, out);
}

// Round 6
// 142.581 us; speedup vs baseline: 1.0877x; 1.0877x over previous
//
#include <hip/hip_runtime.h>

// FullScan via bf16 MFMA 32x32x16, full-M packing.
// out[k,t] = sum_{d<16,w<64} x[d,t+w]*P[k,d,w], K=8, L=1e6.
// M=32 rows = (k, tap-group g): row m = k + 8g (g covers taps [16g,16g+16)).
//   D_g[k](s) = sum_{c<16,d} P[k,d,16g+c] x[d,s+c]
//   out[k,t]  = sum_g D_g[k](t + 16g)
// Chunk c: reduction r = d. Lane l: n=l&31, h=l>>5; B frag elem j: r=8h+j ->
// 8 contiguous d -> aligned ds_read_b128 from d-major xs[row(pos)][16].
// C/D: col=lane&31, row=(reg&3)+8*(reg>>2)+4h => reg kk+4g = D_g[kk+4h](n).
// R6: (a) edge blocks back in mid grid (R5 exposed them serially: -25us);
//     (b) launch_bounds(256,4) -> 4 blocks/CU (LDS 141/160 KB);
//     (c) XOR-row swizzle row=pos^((pos>>3)&3) + half-swizzle (pos>>2)&1:
//         the 8-lane same-bank-group sets now spread over 4 groups x 2
//         halves -> ~2-way (free) instead of 4-way (1.58x).

constexpr int D    = 16;
constexpr int L    = 1000000;
constexpr int W    = 64;
constexpr int K    = 8;
constexpr int PADL = 31;
constexpr int NMID = L - W + 1;          // 999937
constexpr int TPB  = 256;                // 4 waves
constexpr int OTW  = 8;                  // out 32-pos tiles per wave
constexpr int CTW  = OTW + 2;            // computed tiles per wave
constexpr int BLK_OUT = 4 * OTW * 32;    // 1024 positions per block
constexpr int XS   = 1104;               // staged positions (need 1103)
constexpr int NBLK = (NMID + BLK_OUT - 1) / BLK_OUT;   // 977
constexpr int NGRID = NBLK + K;          // +8 hidden edge blocks

typedef __attribute__((ext_vector_type(8)))  short short8;
typedef __attribute__((ext_vector_type(16))) float floatx16;

__device__ __forceinline__ unsigned short f2bf(float f) {
    union { float f; unsigned u; } v; v.f = f;
    unsigned u = v.u + 0x7fff + ((v.u >> 16) & 1);   // RNE
    return (unsigned short)(u >> 16);
}

// Bank-decorrelating row permutation (bits 0-1 ^= bits 3-4; bijective, stays
// within any 32-aligned band so row < XS holds).
__device__ __forceinline__ int xrow(int pos) { return pos ^ ((pos >> 3) & 3); }

__global__ __launch_bounds__(TPB, 4) void fullscan_mid(
    const float* __restrict__ x, const float* __restrict__ P,
    const unsigned short* __restrict__ afr, float* __restrict__ out)
{
    __shared__ __align__(16) unsigned short xs[XS * 16];   // 35328 B
    const int bid = blockIdx.x;
    const int tid = threadIdx.x;

    if (bid >= NBLK) {
        // Edge block (hidden under the big grid): k = bid-NBLK, fp32 exact.
        const int k = bid - NBLK;
        const int j = tid;
        if (j < PADL) {
            float acc = 0.0f;
            for (int m = 0; m <= 32 + j; ++m)
#pragma unroll
                for (int d = 0; d < D; ++d)
                    acc = fmaf(x[d * L + m], P[(k * D + d) * W + m], acc);
            out[k * L + j] = acc;
        } else if (j < 2 * PADL + 1) {
            const int jj = j - PADL;                  // 0..31
            float acc = 0.0f;
            for (int m = jj + 1; m < W; ++m)
#pragma unroll
                for (int d = 0; d < D; ++d)
                    acc = fmaf(x[d * L + (L - W) + m], P[(k * D + d) * W + m], acc);
            out[k * L + PADL + NMID + jj] = acc;
        }
        return;
    }

    const int s0   = bid * BLK_OUT;
    const int lane = tid & 63;
    const int wv   = tid >> 6;

    // ---- Stage x -> LDS (bf16, d-major, swizzled), MLP depth 16 ----
    {
        const int pl = tid & 63;
        const int dq = tid >> 6;            // d-quad 0..3
        const float* xr0 = x + (4 * dq + 0) * L + s0;
        const float* xr1 = x + (4 * dq + 1) * L + s0;
        const float* xr2 = x + (4 * dq + 2) * L + s0;
        const float* xr3 = x + (4 * dq + 3) * L + s0;
#pragma unroll 1
        for (int b0 = 0; b0 < XS; b0 += 256) {
            float v[4][4];
#pragma unroll
            for (int s = 0; s < 4; ++s) {
                const int pos = b0 + 64 * s + pl;
                const bool ok = (pos < XS) && (s0 + pos < L);
                v[s][0] = ok ? xr0[pos] : 0.0f;
                v[s][1] = ok ? xr1[pos] : 0.0f;
                v[s][2] = ok ? xr2[pos] : 0.0f;
                v[s][3] = ok ? xr3[pos] : 0.0f;
            }
#pragma unroll
            for (int s = 0; s < 4; ++s) {
                const int pos = b0 + 64 * s + pl;
                if (pos < XS) {
                    unsigned long long w =
                        (unsigned long long)f2bf(v[s][0])
                      | ((unsigned long long)f2bf(v[s][1]) << 16)
                      | ((unsigned long long)f2bf(v[s][2]) << 32)
                      | ((unsigned long long)f2bf(v[s][3]) << 48);
                    const int swz = (pos >> 2) & 1;
                    *(unsigned long long*)
                        &xs[xrow(pos) * 16 + ((dq * 4) ^ (swz * 8))] = w;
                }
            }
        }
    }

    // Resident A fragments (issued after staging loads; latency hides under
    // the barrier wait).
    short8 A[16];
#pragma unroll
    for (int c = 0; c < 16; ++c)
        A[c] = *(const short8*)(afr + (c * 64 + lane) * 8);

    __syncthreads();

    const int n  = lane & 31;
    const int h  = lane >> 5;
    const int hb = h * 8;
    const int wbase = wv * OTW;             // first local out-tile of this wave

    floatx16 accW[3];

#pragma unroll
    for (int jj = 0; jj < CTW; ++jj) {
        floatx16 acc;
#pragma unroll
        for (int r = 0; r < 16; ++r) acc[r] = 0.0f;
        const int p0 = (wbase + jj) * 32 + n;

        // Software-pipelined chunk loop: prefetch B for c+1 before MFMA c.
        short8 Bc = *(const short8*)
            &xs[xrow(p0) * 16 + (hb ^ (((p0 >> 2) & 1) * 8))];
#pragma unroll
        for (int c = 0; c < 16; ++c) {
            short8 Bn = Bc;
            if (c < 15) {
                const int pos = p0 + c + 1;
                Bn = *(const short8*)
                    &xs[xrow(pos) * 16 + (hb ^ (((pos >> 2) & 1) * 8))];
            }
            acc = __builtin_amdgcn_mfma_f32_32x32x16_bf16(A[c], Bc, acc, 0, 0, 0);
            Bc = Bn;
        }
        accW[jj % 3] = acc;

        if (jj >= 2) {
            const int ot = jj - 2;
            const floatx16 a0 = accW[(jj - 2) % 3];   // tile ot
            const floatx16 a1 = accW[(jj - 1) % 3];   // tile ot+1
            const floatx16 a2 = accW[jj % 3];         // tile ot+2
            const int t = s0 + (wbase + ot) * 32 + n;
#pragma unroll
            for (int kk = 0; kk < 4; ++kk) {
                const float g1t = (n >= 16) ? a0[kk + 4]  : a1[kk + 4];
                const float g3t = (n >= 16) ? a1[kk + 12] : a2[kk + 12];
                const float v = a0[kk] + a1[kk + 8]
                              + __shfl_xor(g1t, 16, 64)
                              + __shfl_xor(g3t, 16, 64);
                if (t < NMID)
                    out[(kk + 4 * h) * L + PADL + t] = v;
            }
        }
    }
}

// Prep: A-fragment table only. afr[c][lane][j] = bf16(P[k, d, w]),
// m=lane&31, h=lane>>5, k=m&7, g=m>>3, d=8h+j, w=16g+c.
__global__ void fullscan_prep(const float* __restrict__ P,
                              unsigned short* __restrict__ afr)
{
    const int u = blockIdx.x * 256 + threadIdx.x;   // 32 blocks x 256 = 8192
    const int c = u >> 9, lane = (u >> 3) & 63, j = u & 7;
    const int m = lane & 31, h = lane >> 5;
    const int k = m & 7, g = m >> 3;
    const int d = 8 * h + j;
    const int w = 16 * g + c;
    afr[u] = f2bf(P[(k * D + d) * W + w]);
}

extern "C" void kernel_launch(void* const* d_in, const int* in_sizes, int n_in,
                              void* d_out, int out_size, void* d_ws, size_t ws_size,
                              hipStream_t stream)
{
    const float* x = (const float*)d_in[0];   // (D, L)
    const float* P = (const float*)d_in[1];   // (K, D, W)
    float* out = (float*)d_out;
    unsigned short* afr = (unsigned short*)d_ws;   // 16 KB

    hipLaunchKernelGGL(fullscan_prep, dim3(32), dim3(256), 0, stream, P, afr);
    hipLaunchKernelGGL(fullscan_mid, dim3(NGRID), dim3(TPB), 0, stream,
                       x, P, afr, out);
}